// Round 5
// baseline (1741.445 us; speedup 1.0000x reference)
//
#include <hip/hip_runtime.h>
#include <stdint.h>

// Problem constants (from reference setup_inputs)
#define BB 4
#define SS 512
#define EE 64
#define VV 50257
#define KK 250              // k_val
#define NROWS (BB * SS)     // 2048
#define NB4 ((NROWS * VV) / 4)  // 25,731,584 float4s, exact (NROWS*VV % 4 == 0)
#define RCAP 2048           // per-row candidate capacity in d_ws
// STEP_SIZE = 0.1 -> multiply by 10; TEMP = 1.0 -> no-op

// Float-domain pre-filter threshold for the fast path. fkey(2.0f)=0xC0000000.
// Correctness does NOT depend on it: rows with <KK or >RCAP survivors take an
// exact full-row fallback in select_kernel.
#define THR0 2.0f
#define K0 0xC0000000u
#define BIN0 3072u          // K0 >> 20

typedef float float4n __attribute__((ext_vector_type(4)));

__device__ __forceinline__ unsigned fkey(float f) {
    // monotonic map: larger float -> larger unsigned
    unsigned u = __float_as_uint(f);
    return (u & 0x80000000u) ? ~u : (u | 0x80000000u);
}

// ---------------- kernel 0: zero the per-row counters ----------------
__global__ void zero_cnt(unsigned* __restrict__ cnt) {
    cnt[blockIdx.x * blockDim.x + threadIdx.x] = 0u;
}

// ---------------- kernel 1: pure streaming filter ----------------
// Flat grid-stride over the whole logits array as float4s. No LDS, no
// barriers. Survivors (~1 in 45) append to per-row global candidate lists.
__global__ __launch_bounds__(256)
void filter_kernel(const float4n* __restrict__ lg4,
                   unsigned long long* __restrict__ cand,
                   unsigned* __restrict__ cnt)
{
    const int S = gridDim.x * blockDim.x;
    int j = blockIdx.x * blockDim.x + threadIdx.x;

    auto emit = [&](float f, int e) {
        if (f >= THR0) {
            unsigned row = (unsigned)e / VV;          // compiler magic-div, exact
            unsigned col = (unsigned)e - row * VV;
            unsigned p = atomicAdd(&cnt[row], 1u);
            if (p < RCAP)
                cand[(size_t)row * RCAP + p] =
                    ((unsigned long long)fkey(f) << 32) | (unsigned)(~col);
        }
    };

    for (; j + 7 * S < NB4; j += 8 * S) {
        float4n v0 = __builtin_nontemporal_load(&lg4[j]);
        float4n v1 = __builtin_nontemporal_load(&lg4[j + S]);
        float4n v2 = __builtin_nontemporal_load(&lg4[j + 2 * S]);
        float4n v3 = __builtin_nontemporal_load(&lg4[j + 3 * S]);
        float4n v4 = __builtin_nontemporal_load(&lg4[j + 4 * S]);
        float4n v5 = __builtin_nontemporal_load(&lg4[j + 5 * S]);
        float4n v6 = __builtin_nontemporal_load(&lg4[j + 6 * S]);
        float4n v7 = __builtin_nontemporal_load(&lg4[j + 7 * S]);
        int e0 = 4 * j,           e1 = 4 * (j + S),     e2 = 4 * (j + 2 * S), e3 = 4 * (j + 3 * S);
        int e4 = 4 * (j + 4 * S), e5 = 4 * (j + 5 * S), e6 = 4 * (j + 6 * S), e7 = 4 * (j + 7 * S);
        emit(v0.x, e0 + 0); emit(v0.y, e0 + 1); emit(v0.z, e0 + 2); emit(v0.w, e0 + 3);
        emit(v1.x, e1 + 0); emit(v1.y, e1 + 1); emit(v1.z, e1 + 2); emit(v1.w, e1 + 3);
        emit(v2.x, e2 + 0); emit(v2.y, e2 + 1); emit(v2.z, e2 + 2); emit(v2.w, e2 + 3);
        emit(v3.x, e3 + 0); emit(v3.y, e3 + 1); emit(v3.z, e3 + 2); emit(v3.w, e3 + 3);
        emit(v4.x, e4 + 0); emit(v4.y, e4 + 1); emit(v4.z, e4 + 2); emit(v4.w, e4 + 3);
        emit(v5.x, e5 + 0); emit(v5.y, e5 + 1); emit(v5.z, e5 + 2); emit(v5.w, e5 + 3);
        emit(v6.x, e6 + 0); emit(v6.y, e6 + 1); emit(v6.z, e6 + 2); emit(v6.w, e6 + 3);
        emit(v7.x, e7 + 0); emit(v7.y, e7 + 1); emit(v7.z, e7 + 2); emit(v7.w, e7 + 3);
    }
    for (; j < NB4; j += S) {
        float4n v = __builtin_nontemporal_load(&lg4[j]);
        int e = 4 * j;
        emit(v.x, e + 0); emit(v.y, e + 1); emit(v.z, e + 2); emit(v.w, e + 3);
    }
}

// ---------------- kernel 2: per-row exact select + sort + epilogue ----------------
__global__ __launch_bounds__(256)
void select_kernel(const float* __restrict__ gx,
                   const float* __restrict__ cb,
                   const float* __restrict__ W,
                   const float* __restrict__ logits,
                   const unsigned long long* __restrict__ cand,
                   const unsigned* __restrict__ cnt,
                   float* __restrict__ out0,   // filtered [B*S, K]
                   float* __restrict__ out1)   // ids as float [B*S, K]
{
    __shared__ unsigned long long cs[RCAP];    // 16 KB; fallback hist4[4096] aliases
    __shared__ unsigned long long buf2[512];   // 4 KB; fast-path hist[1024] aliases
    __shared__ unsigned chunkSum[256];         // 1 KB
    __shared__ float gx_s[EE], cb_s[EE];
    __shared__ unsigned sThreshKey, sCnt, sCnt2;

    const int row = blockIdx.x;
    const int tid = threadIdx.x;
    const float* rp = logits + (size_t)row * VV;
    unsigned* hist = (unsigned*)buf2;          // 1024 bins (fast path)

    for (int i = tid; i < 1024; i += 256) hist[i] = 0u;
    if (tid < EE) {
        gx_s[tid] = gx[(size_t)row * EE + tid];
        cb_s[tid] = cb[(size_t)row * EE + tid];
    }
    if (tid == 0) { sCnt = 0u; sCnt2 = 0u; }
    __syncthreads();

    const unsigned n_total = cnt[row];
    unsigned long long* srt;
    unsigned P;

    if (n_total >= KK && n_total <= RCAP) {
        // ================= FAST PATH =================
        for (unsigned i = tid; i < n_total; i += 256)
            cs[i] = cand[(size_t)row * RCAP + i];
        __syncthreads();

        for (unsigned i = tid; i < n_total; i += 256)
            atomicAdd(&hist[((unsigned)(cs[i] >> 32) >> 20) - BIN0], 1u);
        __syncthreads();

        chunkSum[tid] = hist[tid * 4] + hist[tid * 4 + 1] + hist[tid * 4 + 2] + hist[tid * 4 + 3];
        __syncthreads();
        {
            unsigned g = 0;
            for (int u = tid + 1; u < 256; ++u) g += chunkSum[u];
            unsigned csm = chunkSum[tid];
            if (g < KK && g + csm >= KK) {
                unsigned cum = g;
                #pragma unroll
                for (int b = 3; b >= 0; --b) {
                    unsigned c = hist[tid * 4 + b];
                    if (cum + c >= KK) { sThreshKey = ((unsigned)(tid * 4 + b) + BIN0) << 20; break; }
                    cum += c;
                }
            }
        }
        __syncthreads();
        const unsigned keyT = sThreshKey;
        __syncthreads();   // hist (aliases buf2) dead; buf2 may now be written

        for (unsigned i = tid; i < n_total; i += 256) {
            unsigned long long c = cs[i];
            if ((unsigned)(c >> 32) >= keyT) {
                unsigned p = atomicAdd(&sCnt2, 1u);
                if (p < 512) buf2[p] = c;
            }
        }
        __syncthreads();
        unsigned nc = sCnt2;
        if (nc <= 512) {
            srt = buf2;
            P = 256; while (P < nc) P <<= 1;
            for (unsigned i = nc + tid; i < P; i += 256) buf2[i] = 0ull;
        } else {
            srt = cs;
            P = 256; while (P < n_total) P <<= 1;
            for (unsigned i = n_total + tid; i < P; i += 256) cs[i] = 0ull;
        }
        __syncthreads();
    } else {
        // ============ EXACT FALLBACK: full-row rescan (never taken on N(0,1)) ============
        unsigned* hist4 = (unsigned*)cs;   // 4096 bins alias cs exactly (16 KB)
        for (int i = tid; i < 4096; i += 256) hist4[i] = 0u;
        __syncthreads();

        const int mis  = row & 3;          // (row*VV) % 4 == row % 4
        const int peel = (4 - mis) & 3;
        const int nb   = (VV - peel) >> 2;
        const int tail0 = peel + nb * 4;
        const float4n* rp4 = (const float4n*)(rp + peel);

        if (tid < peel) atomicAdd(&hist4[fkey(rp[tid]) >> 20], 1u);
        for (int i = tid; i < nb; i += 256) {
            float4n v = rp4[i];
            atomicAdd(&hist4[fkey(v.x) >> 20], 1u);
            atomicAdd(&hist4[fkey(v.y) >> 20], 1u);
            atomicAdd(&hist4[fkey(v.z) >> 20], 1u);
            atomicAdd(&hist4[fkey(v.w) >> 20], 1u);
        }
        for (int t = tail0 + tid; t < VV; t += 256) atomicAdd(&hist4[fkey(rp[t]) >> 20], 1u);
        __syncthreads();

        {
            unsigned csum = 0;
            #pragma unroll
            for (int b = 0; b < 16; ++b) csum += hist4[tid * 16 + b];
            chunkSum[tid] = csum;
        }
        __syncthreads();
        {
            unsigned g = 0;
            for (int u = tid + 1; u < 256; ++u) g += chunkSum[u];
            unsigned csm = chunkSum[tid];
            if (g < KK && g + csm >= KK) {
                unsigned cum = g;
                #pragma unroll
                for (int b = 15; b >= 0; --b) {
                    unsigned c = hist4[tid * 16 + b];
                    if (cum + c >= KK) { sThreshKey = ((unsigned)(tid * 16 + b)) << 20; break; }
                    cum += c;
                }
            }
        }
        __syncthreads();
        const unsigned keyT = sThreshKey;
        __syncthreads();   // hist4 aliases cs -> drain before collection writes

        auto emit2 = [&](unsigned k, int idx) {
            if (k >= keyT) {
                unsigned p = atomicAdd(&sCnt, 1u);
                if (p < RCAP) cs[p] = ((unsigned long long)k << 32) | (unsigned)(~idx);
            }
        };
        if (tid < peel) emit2(fkey(rp[tid]), tid);
        for (int i = tid; i < nb; i += 256) {
            float4n v = rp4[i];
            int ia = peel + 4 * i;
            emit2(fkey(v.x), ia + 0); emit2(fkey(v.y), ia + 1);
            emit2(fkey(v.z), ia + 2); emit2(fkey(v.w), ia + 3);
        }
        for (int t = tail0 + tid; t < VV; t += 256) emit2(fkey(rp[t]), t);
        __syncthreads();
        unsigned n1 = sCnt; if (n1 > RCAP) n1 = RCAP;
        srt = cs;
        P = 256; while (P < n1) P <<= 1;
        for (unsigned i = n1 + tid; i < P; i += 256) cs[i] = 0ull;
        __syncthreads();
    }

    // ---- bitonic sort descending on composite (key<<32 | ~idx) ----
    for (unsigned k = 2; k <= P; k <<= 1) {
        for (unsigned jj = k >> 1; jj > 0; jj >>= 1) {
            for (unsigned i2 = tid; i2 < P; i2 += 256) {
                unsigned l = i2 ^ jj;
                if (l > i2) {
                    unsigned long long a = srt[i2], b = srt[l];
                    bool up = ((i2 & k) == 0);
                    if (up ? (a < b) : (a > b)) { srt[i2] = b; srt[l] = a; }
                }
            }
            __syncthreads();
        }
    }

    // ---- epilogue: proposal value at the K selected ids ----
    if (tid < KK) {
        float gxcb = 0.f, cbn = 0.f;
        #pragma unroll
        for (int e = 0; e < EE; ++e) { gxcb += gx_s[e] * cb_s[e]; cbn += cb_s[e] * cb_s[e]; }

        unsigned long long ck = srt[tid];
        unsigned v = ~((unsigned)ck);
        const float4* Wv = (const float4*)(W + (size_t)v * EE);
        float d1 = 0.f, d2 = 0.f, wn = 0.f;
        #pragma unroll
        for (int j2 = 0; j2 < 16; ++j2) {
            float4 w = Wv[j2];
            float a0 = gx_s[4*j2+0], a1 = gx_s[4*j2+1], a2 = gx_s[4*j2+2], a3 = gx_s[4*j2+3];
            float b0 = cb_s[4*j2+0], b1 = cb_s[4*j2+1], b2 = cb_s[4*j2+2], b3 = cb_s[4*j2+3];
            d1 += a0*w.x + a1*w.y + a2*w.z + a3*w.w;
            d2 += b0*w.x + b1*w.y + b2*w.z + b3*w.w;
            wn += w.x*w.x + w.y*w.y + w.z*w.z + w.w*w.w;
        }
        // dist = 0.5*(t1_1 - t1_2) + (t2_1 - 2*t2_2 + t2_3)/0.1 ; out = -dist / TEMP
        float unf = -(0.5f * (d1 - gxcb) + (wn - 2.0f * d2 + cbn) * 10.0f);
        out0[(size_t)row * KK + tid] = unf;
        out1[(size_t)row * KK + tid] = (float)v;
    }
}

extern "C" void kernel_launch(void* const* d_in, const int* in_sizes, int n_in,
                              void* d_out, int out_size, void* d_ws, size_t ws_size,
                              hipStream_t stream) {
    const float* gx = (const float*)d_in[0];      // [B,S,E]
    const float* cb = (const float*)d_in[1];      // [B,S,E]
    const float* W  = (const float*)d_in[2];      // [V,E]
    const float* lg = (const float*)d_in[3];      // [B,S,V]
    float* out0 = (float*)d_out;                       // filtered, 512000 floats
    float* out1 = out0 + (size_t)BB * SS * KK;         // ids as float, 512000

    // d_ws layout: cnt[2048] (8 KB, padded to 8192 B) ; cand[2048][RCAP] (33.5 MB)
    unsigned* cnt = (unsigned*)d_ws;
    unsigned long long* cand = (unsigned long long*)((char*)d_ws + 8192);

    hipLaunchKernelGGL(zero_cnt, dim3(8), dim3(256), 0, stream, cnt);
    hipLaunchKernelGGL(filter_kernel, dim3(2048), dim3(256), 0, stream,
                       (const float4n*)lg, cand, cnt);
    hipLaunchKernelGGL(select_kernel, dim3(NROWS), dim3(256), 0, stream,
                       gx, cb, W, lg, cand, cnt, out0, out1);
}

// Round 6
// 142.667 us; speedup vs baseline: 12.2064x; 12.2064x over previous
//
#include <hip/hip_runtime.h>
#include <stdint.h>

// Problem constants (from reference setup_inputs)
#define BB 4
#define SS 512
#define EE 64
#define VV 50257
#define KK 250              // k_val
#define NROWS (BB * SS)     // 2048
#define RCAP 2048           // per-row candidate capacity in d_ws
#define FCAP 512            // per-half-row-block LDS candidate capacity
// STEP_SIZE = 0.1 -> multiply by 10; TEMP = 1.0 -> no-op

// Float-domain pre-filter threshold. P(N(0,1) >= 2.4) = 0.0082 -> E[412]/row,
// sigma ~20. Correctness does NOT depend on it: rows with <KK or >RCAP
// survivors (incl. block-overflow poison) take an exact full-row fallback.
#define THRF 2.4f

typedef float float4n __attribute__((ext_vector_type(4)));

__device__ __forceinline__ unsigned fkey(float f) {
    // monotonic map: larger float -> larger unsigned
    unsigned u = __float_as_uint(f);
    return (u & 0x80000000u) ? ~u : (u | 0x80000000u);
}

// ---------------- kernel 0: zero the per-row counters ----------------
__global__ void zero_cnt(unsigned* __restrict__ cnt) {
    cnt[blockIdx.x * blockDim.x + threadIdx.x] = 0u;
}

// ---------------- kernel 1: streaming filter, half-row per block ----------------
// Survivors buffered in LDS; ONE global atomic per block at flush (4096 total).
__global__ __launch_bounds__(256, 8)
void filter_kernel(const float* __restrict__ lg,
                   unsigned long long* __restrict__ cand,
                   unsigned* __restrict__ cnt)
{
    __shared__ unsigned long long lbuf[FCAP];
    __shared__ unsigned lcnt, sBase;
    const int bid = blockIdx.x, tid = threadIdx.x;
    const int row = bid >> 1, half = bid & 1;
    if (tid == 0) lcnt = 0u;
    __syncthreads();

    const size_t rowbase = (size_t)row * VV;
    const unsigned p  = (4u - ((unsigned)rowbase & 3u)) & 3u;  // peel to 16B align
    const unsigned F  = (VV - p) >> 2;                         // aligned float4 count
    const unsigned F0 = F >> 1;
    const float4n* rp4 = (const float4n*)(lg + rowbase + p);

    auto emit = [&](float f, unsigned col) {
        if (f >= THRF) {
            unsigned q = atomicAdd(&lcnt, 1u);
            if (q < FCAP)
                lbuf[q] = ((unsigned long long)fkey(f) << 32) | (unsigned)(~col);
        }
    };

    const unsigned lo = half ? F0 : 0u;
    const unsigned hi = half ? F  : F0;

    if (half == 0 && tid < (int)p) emit(lg[rowbase + tid], tid);   // peel scalars

    unsigned i = lo + tid;
    for (; i + 768u < hi; i += 1024u) {
        float4n a = __builtin_nontemporal_load(&rp4[i]);
        float4n b = __builtin_nontemporal_load(&rp4[i + 256u]);
        float4n c = __builtin_nontemporal_load(&rp4[i + 512u]);
        float4n d = __builtin_nontemporal_load(&rp4[i + 768u]);
        // max3-friendly 16-way max tree: 8 ops per 16 elements
        float t0 = fmaxf(fmaxf(a.x, a.y), a.z);
        float t1 = fmaxf(fmaxf(a.w, b.x), b.y);
        float t2 = fmaxf(fmaxf(b.z, b.w), c.x);
        float t3 = fmaxf(fmaxf(c.y, c.z), c.w);
        float t4 = fmaxf(fmaxf(d.x, d.y), d.z);
        float u0 = fmaxf(fmaxf(t0, t1), t2);
        float u1 = fmaxf(fmaxf(t3, t4), d.w);
        if (fmaxf(u0, u1) >= THRF) {           // ~12% of iterations
            unsigned c0 = p + 4u*i, c1 = p + 4u*(i+256u), c2 = p + 4u*(i+512u), c3 = p + 4u*(i+768u);
            emit(a.x, c0+0); emit(a.y, c0+1); emit(a.z, c0+2); emit(a.w, c0+3);
            emit(b.x, c1+0); emit(b.y, c1+1); emit(b.z, c1+2); emit(b.w, c1+3);
            emit(c.x, c2+0); emit(c.y, c2+1); emit(c.z, c2+2); emit(c.w, c2+3);
            emit(d.x, c3+0); emit(d.y, c3+1); emit(d.z, c3+2); emit(d.w, c3+3);
        }
    }
    for (; i < hi; i += 256u) {
        float4n a = __builtin_nontemporal_load(&rp4[i]);
        float m = fmaxf(fmaxf(a.x, a.y), fmaxf(a.z, a.w));
        if (m >= THRF) {
            unsigned c0 = p + 4u*i;
            emit(a.x, c0+0); emit(a.y, c0+1); emit(a.z, c0+2); emit(a.w, c0+3);
        }
    }
    if (half == 1) {                                              // tail scalars
        for (unsigned t = p + 4u*F + tid; t < VV; t += 256u) emit(lg[rowbase + t], t);
    }

    __syncthreads();
    const unsigned total = lcnt;
    const unsigned m = total > FCAP ? FCAP : total;
    if (tid == 0)   // overflow poisons cnt -> forces exact fallback in select
        sBase = atomicAdd(&cnt[row], total > FCAP ? 0x10000000u : total);
    __syncthreads();
    const unsigned base = sBase;
    for (unsigned j = tid; j < m; j += 256u) {
        unsigned dst = base + j;
        if (dst < RCAP) cand[(size_t)row * RCAP + dst] = lbuf[j];
    }
}

// ---------------- kernel 2: per-row sort + epilogue ----------------
__global__ __launch_bounds__(256, 4)
void select_kernel(const float* __restrict__ gx,
                   const float* __restrict__ cb,
                   const float* __restrict__ W,
                   const float* __restrict__ logits,
                   const unsigned long long* __restrict__ cand,
                   const unsigned* __restrict__ cnt,
                   float* __restrict__ out0,   // filtered [B*S, K]
                   float* __restrict__ out1)   // ids as float [B*S, K]
{
    __shared__ unsigned long long cs[RCAP];    // 16 KB; fallback hist4[4096] aliases
    __shared__ unsigned long long buf[FCAP];   // 4 KB fast-path sort buffer
    __shared__ unsigned chunkSum[256];         // fallback only
    __shared__ float gx_s[EE], cb_s[EE];
    __shared__ unsigned sThreshKey, sCnt;

    const int row = blockIdx.x;
    const int tid = threadIdx.x;
    const float* rp = logits + (size_t)row * VV;

    if (tid < EE) {
        gx_s[tid] = gx[(size_t)row * EE + tid];
        cb_s[tid] = cb[(size_t)row * EE + tid];
    }

    const unsigned n_total = cnt[row];
    unsigned long long* srt;
    unsigned P;

    if (n_total >= KK && n_total <= FCAP) {
        // ---- fast path: direct sort of <=512 candidates, no histogram ----
        for (unsigned i = tid; i < n_total; i += 256) buf[i] = cand[(size_t)row * RCAP + i];
        P = 256; while (P < n_total) P <<= 1;
        for (unsigned i = n_total + tid; i < P; i += 256) buf[i] = 0ull;
        srt = buf;
        __syncthreads();
    } else if (n_total > FCAP && n_total <= RCAP) {
        // ---- mid path (rare): sort up to 2048 directly ----
        for (unsigned i = tid; i < n_total; i += 256) cs[i] = cand[(size_t)row * RCAP + i];
        P = 256; while (P < n_total) P <<= 1;
        for (unsigned i = n_total + tid; i < P; i += 256) cs[i] = 0ull;
        srt = cs;
        __syncthreads();
    } else {
        // ====== EXACT FALLBACK: full-row rescan (never taken on N(0,1)) ======
        unsigned* hist4 = (unsigned*)cs;       // 4096 bins alias cs (16 KB)
        for (int i = tid; i < 4096; i += 256) hist4[i] = 0u;
        if (tid == 0) sCnt = 0u;
        __syncthreads();

        const unsigned p  = (4u - ((unsigned)((size_t)row * VV) & 3u)) & 3u;
        const unsigned nb = (VV - p) >> 2;
        const unsigned tail0 = p + nb * 4u;
        const float4n* rp4 = (const float4n*)(rp + p);

        if (tid < (int)p) atomicAdd(&hist4[fkey(rp[tid]) >> 20], 1u);
        for (unsigned i = tid; i < nb; i += 256) {
            float4n v = rp4[i];
            atomicAdd(&hist4[fkey(v.x) >> 20], 1u);
            atomicAdd(&hist4[fkey(v.y) >> 20], 1u);
            atomicAdd(&hist4[fkey(v.z) >> 20], 1u);
            atomicAdd(&hist4[fkey(v.w) >> 20], 1u);
        }
        for (unsigned t = tail0 + tid; t < VV; t += 256) atomicAdd(&hist4[fkey(rp[t]) >> 20], 1u);
        __syncthreads();

        {
            unsigned csum = 0;
            #pragma unroll
            for (int b = 0; b < 16; ++b) csum += hist4[tid * 16 + b];
            chunkSum[tid] = csum;
        }
        __syncthreads();
        {
            unsigned g = 0;
            for (int u = tid + 1; u < 256; ++u) g += chunkSum[u];
            unsigned csm = chunkSum[tid];
            if (g < KK && g + csm >= KK) {
                unsigned cum = g;
                #pragma unroll
                for (int b = 15; b >= 0; --b) {
                    unsigned c = hist4[tid * 16 + b];
                    if (cum + c >= KK) { sThreshKey = ((unsigned)(tid * 16 + b)) << 20; break; }
                    cum += c;
                }
            }
        }
        __syncthreads();
        const unsigned keyT = sThreshKey;
        __syncthreads();   // hist4 aliases cs -> drain before collection writes

        auto emit2 = [&](unsigned k, unsigned idx) {
            if (k >= keyT) {
                unsigned q = atomicAdd(&sCnt, 1u);
                if (q < RCAP) cs[q] = ((unsigned long long)k << 32) | (unsigned)(~idx);
            }
        };
        if (tid < (int)p) emit2(fkey(rp[tid]), tid);
        for (unsigned i = tid; i < nb; i += 256) {
            float4n v = rp4[i];
            unsigned ia = p + 4u * i;
            emit2(fkey(v.x), ia + 0); emit2(fkey(v.y), ia + 1);
            emit2(fkey(v.z), ia + 2); emit2(fkey(v.w), ia + 3);
        }
        for (unsigned t = tail0 + tid; t < VV; t += 256) emit2(fkey(rp[t]), t);
        __syncthreads();
        unsigned n1 = sCnt; if (n1 > RCAP) n1 = RCAP;
        srt = cs;
        P = 256; while (P < n1) P <<= 1;
        for (unsigned i = n1 + tid; i < P; i += 256) cs[i] = 0ull;
        __syncthreads();
    }

    // ---- bitonic sort descending on composite (key<<32 | ~idx) ----
    for (unsigned k = 2; k <= P; k <<= 1) {
        for (unsigned jj = k >> 1; jj > 0; jj >>= 1) {
            for (unsigned i2 = tid; i2 < P; i2 += 256) {
                unsigned l = i2 ^ jj;
                if (l > i2) {
                    unsigned long long a = srt[i2], b = srt[l];
                    bool up = ((i2 & k) == 0);
                    if (up ? (a < b) : (a > b)) { srt[i2] = b; srt[l] = a; }
                }
            }
            __syncthreads();
        }
    }

    // ---- epilogue: proposal value at the K selected ids ----
    if (tid < KK) {
        float gxcb = 0.f, cbn = 0.f;
        #pragma unroll
        for (int e = 0; e < EE; ++e) { gxcb += gx_s[e] * cb_s[e]; cbn += cb_s[e] * cb_s[e]; }

        unsigned long long ck = srt[tid];
        unsigned v = ~((unsigned)ck);
        const float4* Wv = (const float4*)(W + (size_t)v * EE);
        float d1 = 0.f, d2 = 0.f, wn = 0.f;
        #pragma unroll
        for (int j2 = 0; j2 < 16; ++j2) {
            float4 w = Wv[j2];
            float a0 = gx_s[4*j2+0], a1 = gx_s[4*j2+1], a2 = gx_s[4*j2+2], a3 = gx_s[4*j2+3];
            float b0 = cb_s[4*j2+0], b1 = cb_s[4*j2+1], b2 = cb_s[4*j2+2], b3 = cb_s[4*j2+3];
            d1 += a0*w.x + a1*w.y + a2*w.z + a3*w.w;
            d2 += b0*w.x + b1*w.y + b2*w.z + b3*w.w;
            wn += w.x*w.x + w.y*w.y + w.z*w.z + w.w*w.w;
        }
        // dist = 0.5*(t1_1 - t1_2) + (t2_1 - 2*t2_2 + t2_3)/0.1 ; out = -dist / TEMP
        float unf = -(0.5f * (d1 - gxcb) + (wn - 2.0f * d2 + cbn) * 10.0f);
        out0[(size_t)row * KK + tid] = unf;
        out1[(size_t)row * KK + tid] = (float)v;
    }
}

extern "C" void kernel_launch(void* const* d_in, const int* in_sizes, int n_in,
                              void* d_out, int out_size, void* d_ws, size_t ws_size,
                              hipStream_t stream) {
    const float* gx = (const float*)d_in[0];      // [B,S,E]
    const float* cb = (const float*)d_in[1];      // [B,S,E]
    const float* W  = (const float*)d_in[2];      // [V,E]
    const float* lg = (const float*)d_in[3];      // [B,S,V]
    float* out0 = (float*)d_out;                       // filtered, 512000 floats
    float* out1 = out0 + (size_t)BB * SS * KK;         // ids as float, 512000

    // d_ws layout: cnt[2048] (8 KB pad) ; cand[2048][RCAP] u64 (33.5 MB)
    unsigned* cnt = (unsigned*)d_ws;
    unsigned long long* cand = (unsigned long long*)((char*)d_ws + 8192);

    hipLaunchKernelGGL(zero_cnt, dim3(8), dim3(256), 0, stream, cnt);
    hipLaunchKernelGGL(filter_kernel, dim3(2 * NROWS), dim3(256), 0, stream,
                       lg, cand, cnt);
    hipLaunchKernelGGL(select_kernel, dim3(NROWS), dim3(256), 0, stream,
                       gx, cb, W, lg, cand, cnt, out0, out1);
}